// Round 6
// baseline (1960.471 us; speedup 1.0000x reference)
//
#include <hip/hip_runtime.h>
#include <cstddef>
#include <cstdint>

// Problem constants
#define kB 32
#define kT 2048
#define kIn 512
#define kH 256
#define kBeta 0.85f
#define kThr 1.0f

// Fused-kernel layout: blocks [0, N_SCAN) = scan (one per batch),
// blocks [N_SCAN, N_SCAN+N_GEMM) = GEMM tiles (256x256, t-major order).
#define N_SCAN kB
#define N_GEMM (kB * 8)        // 32 b x 8 t_tiles (256 rows each)
#define FLAGS_PER_B 8
#define NTB (kT / 8)           // 256 bursts of 8 steps

// GEMM tile config: 256x256 tile, BK=16, 1024 threads, 8x8 micro-tile.
#define GBM 256
#define GBK 16
#define GLDA 260               // +4 pad: conflict-free transposed staging

// scan smem map (float offsets)
#define SSTRIDE 260            // pbuf row stride (verbatim R6)
#define SM_SBYTE_F 0           // 2x256 spike bytes = 512 B = 128 floats
#define SM_PBUF  128           // partials: 16 x 260 floats
#define SM_PRING (SM_PBUF + 16 * SSTRIDE)    // 4288: proj ring, 16 slots x 256
#define SM_OBUF  (SM_PRING + 16 * 256)       // 8384: spike outbox, 8 x 256
#define SMEM_SCAN (SM_OBUF + 8 * 256)        // 10432 floats = 41.7 KB
#define SMEM_GEMM (2 * GBK * GLDA)           // 8320 floats
#define SMEM_FLOATS (SMEM_SCAN > SMEM_GEMM ? SMEM_SCAN : SMEM_GEMM)

__device__ __forceinline__ void wait_flag(int* f) {
    // acquire/agent: later proj loads must see the producer XCD's stores
    while (__hip_atomic_load(f, __ATOMIC_ACQUIRE, __HIP_MEMORY_SCOPE_AGENT) == 0) {
        __builtin_amdgcn_s_sleep(2);
    }
}

// Scan barrier: LDS-fence only (lgkmcnt(0) + raw s_barrier), proven in R11.
// Does NOT drain vmcnt, so distributed proj/spike global ops stay in flight
// across barriers. All cross-wave scan traffic is LDS.
__device__ __forceinline__ void scan_bar() {
    asm volatile("s_waitcnt lgkmcnt(0)" ::: "memory");
    __builtin_amdgcn_s_barrier();
}

// quad butterfly halves (doc-verified ds_swizzle BitMode patterns)
__device__ __forceinline__ float swz_xor1(float x) {
    return __int_as_float(__builtin_amdgcn_ds_swizzle(__float_as_int(x), 0x041F));
}
__device__ __forceinline__ float swz_xor2(float x) {
    return __int_as_float(__builtin_amdgcn_ds_swizzle(__float_as_int(x), 0x081F));
}

// ---------------------------------------------------------------------------
// GEMM body: proj tile = x(256xK) @ W_in^T(Kx256) + b_in, then publish flag.
// Verbatim from the verified round-6 kernel (bit-identical proj).
// ---------------------------------------------------------------------------
__device__ void gemm_body(const float* __restrict__ A,
                          const float* __restrict__ W,
                          const float* __restrict__ bias,
                          float* __restrict__ P,
                          int* flags, int gid, float* smem)
{
    float* As = smem;
    float* Bs = smem + GBK * GLDA;
    const int tid = threadIdx.x;
    const int b  = gid & 31;          // t-major tile order: all b at t_tile 0 first
    const int tt = gid >> 5;          // 0..7
    const int bm = b * kT + tt * GBM; // row offset in flattened (B*T)
    const int tx = tid & 31;
    const int ty = tid >> 5;          // 0..31

    float acc[8][8];
#pragma unroll
    for (int i = 0; i < 8; ++i)
#pragma unroll
        for (int j = 0; j < 8; ++j) acc[i][j] = 0.f;

    const int r = tid >> 2, kc = (tid & 3) << 2;

    for (int kb = 0; kb < kIn; kb += GBK) {
        const float4 av = *reinterpret_cast<const float4*>(A + (size_t)(bm + r) * kIn + kb + kc);
        const float4 bv = *reinterpret_cast<const float4*>(W + (size_t)r * kIn + kb + kc);
        __syncthreads();   // previous iteration's LDS reads done
        As[(kc + 0) * GLDA + r] = av.x;
        As[(kc + 1) * GLDA + r] = av.y;
        As[(kc + 2) * GLDA + r] = av.z;
        As[(kc + 3) * GLDA + r] = av.w;
        Bs[(kc + 0) * GLDA + r] = bv.x;
        Bs[(kc + 1) * GLDA + r] = bv.y;
        Bs[(kc + 2) * GLDA + r] = bv.z;
        Bs[(kc + 3) * GLDA + r] = bv.w;
        __syncthreads();

#pragma unroll
        for (int k = 0; k < GBK; ++k) {
            const float4 aa0 = *reinterpret_cast<const float4*>(&As[k * GLDA + ty * 4]);
            const float4 aa1 = *reinterpret_cast<const float4*>(&As[k * GLDA + ty * 4 + 128]);
            const float4 bb0 = *reinterpret_cast<const float4*>(&Bs[k * GLDA + tx * 4]);
            const float4 bb1 = *reinterpret_cast<const float4*>(&Bs[k * GLDA + tx * 4 + 128]);
            const float av8[8] = {aa0.x, aa0.y, aa0.z, aa0.w, aa1.x, aa1.y, aa1.z, aa1.w};
            const float bv8[8] = {bb0.x, bb0.y, bb0.z, bb0.w, bb1.x, bb1.y, bb1.z, bb1.w};
#pragma unroll
            for (int i = 0; i < 8; ++i)
#pragma unroll
                for (int j = 0; j < 8; ++j)
                    acc[i][j] = fmaf(av8[i], bv8[j], acc[i][j]);
        }
    }

    const float4 bl = *reinterpret_cast<const float4*>(bias + tx * 4);
    const float4 bh = *reinterpret_cast<const float4*>(bias + tx * 4 + 128);
#pragma unroll
    for (int i = 0; i < 8; ++i) {
        const int m = bm + ty * 4 + (i & 3) + ((i >> 2) << 7);
        float4 o0, o1;
        o0.x = acc[i][0] + bl.x; o0.y = acc[i][1] + bl.y;
        o0.z = acc[i][2] + bl.z; o0.w = acc[i][3] + bl.w;
        o1.x = acc[i][4] + bh.x; o1.y = acc[i][5] + bh.y;
        o1.z = acc[i][6] + bh.z; o1.w = acc[i][7] + bh.w;
        *reinterpret_cast<float4*>(P + (size_t)m * kH + tx * 4) = o0;
        *reinterpret_cast<float4*>(P + (size_t)m * kH + tx * 4 + 128) = o1;
    }

    __syncthreads();   // all stores executed block-wide
    if (flags && tid == 0) {
        __threadfence();                                  // device-scope release
        atomicAdd(flags + b * FLAGS_PER_B + tt, 1);       // publish (b, tt) ready
    }
}

// ---------------------------------------------------------------------------
// Scan, round 12. Phase-1 fma chains, pbuf layout, 16-leaf tree grouping and
// the contract-off membrane update are arithmetically VERBATIM from the
// verified R6 lineage (bit-identical output). Two structural changes:
//  1) Spikes exchanged as BYTES (double-buffered 256-byte array): phase-1
//     reads its 16 coefficient bytes with ONE broadcast ds_read_b128 and
//     expands via (float)((w>>8N)&0xFF) -- pure VALU, removing the ~700
//     SALU/step (readfirstlane + per-bit scalar extract + nibble branches)
//     that co-limited phase-1. Coefficients exactly 0.0/1.0; dense j-
//     ascending chains == R6's skip version since fmaf(0,V,a)==a.
//  2) Phase-2 distributed over ALL 16 waves: wave w reduces h in
//     [16w,16w+16), 4 lanes per h; lane sub reads partials 4sub..4sub+3
//     (2 lanes/bank = free) forming r_sub = (s0+s1)+(s2+s3); quad butterfly
//     (ds_swizzle xor1, xor2) gives ((r0+r1)+(r2+r3)) -- the exact verified
//     tree; commutativity keeps all 4 replicas bit-equal. Update replicated
//     per-quad; sub==0 lane publishes the spike byte + outbox float.
//  vmem (proj prefetch / spike drain) is spread over all 1024 threads
//  (2 floats each per 8-step burst), issued at ti==0, LDS-written at ti==6,
//  kept in flight across the lgkm-only barriers.
// ---------------------------------------------------------------------------
__device__ void scan_body(float* __restrict__ PO,
                          const float* __restrict__ V,
                          const float* __restrict__ brec,
                          int* flags, float* smem)
{
    uint8_t* sbyte = reinterpret_cast<uint8_t*>(smem + SM_SBYTE_F);  // 2x256 B
    float* pbuf  = smem + SM_PBUF;
    float* pring = smem + SM_PRING;
    float* obuf  = smem + SM_OBUF;

    const int b = blockIdx.x;
    const int tid = threadIdx.x;
    const int w = tid >> 6;         // wave 0..15 = phase-1 k-chunk index
    const int l = tid & 63;
    const int h0 = l << 2;          // phase-1: this thread's 4 h-rows
    const int kc = w << 4;          // phase-1: k base
    const int sub = l & 3;          // phase-2: quarter index
    const int myh = (w << 4) + (l >> 2);   // phase-2: owned neuron

    // V regs: Vr[i][c] = V[h0+i][kc+c]   (64 VGPRs; verbatim R6)
    float Vr[4][16];
#pragma unroll
    for (int i = 0; i < 4; ++i) {
        const float4* vp = reinterpret_cast<const float4*>(V + (size_t)(h0 + i) * kH + kc);
#pragma unroll
        for (int c4 = 0; c4 < 4; ++c4) {
            const float4 v = vp[c4];
            Vr[i][c4 * 4 + 0] = v.x; Vr[i][c4 * 4 + 1] = v.y;
            Vr[i][c4 * 4 + 2] = v.z; Vr[i][c4 * 4 + 3] = v.w;
        }
    }

    const float br = brec[myh];
    float mem = 0.f, spk = 0.f;
    float* po_b = PO + (size_t)b * (size_t)kT * kH;

    if (tid < 128) reinterpret_cast<uint32_t*>(sbyte)[tid] = 0u;  // both slots

    int* bflags = flags ? (flags + b * FLAGS_PER_B) : nullptr;

    // init: all threads stage proj rows 0..7 into ring slots 0..7
    if (bflags) wait_flag(bflags + 0);         // proj tile (b, t<256) ready
    {
        const float2 iv = *reinterpret_cast<const float2*>(po_b + 2 * tid);
        *reinterpret_cast<float2*>(pring + 2 * tid) = iv;
    }
    scan_bar();

    for (int tb = 0; tb < NTB; ++tb) {
        float2 gld;
#pragma unroll
        for (int ti = 0; ti < 8; ++ti) {
            const int t = tb * 8 + ti;

            if (ti == 0) {
                // drain previous burst's spikes: obuf -> global (stores stay
                // in flight; nothing waits on them)
                if (tb > 0) {
                    const float2 d = *reinterpret_cast<const float2*>(obuf + 2 * tid);
                    *reinterpret_cast<float2*>(po_b + (size_t)(tb - 1) * 2048 + 2 * tid) = d;
                }
                // issue next-burst proj loads (consumed at ti==6: ~6 steps
                // in flight >> HBM latency)
                if (tb < NTB - 1) {
                    if (bflags && ((tb + 1) & 31) == 0)
                        wait_flag(bflags + ((tb + 1) >> 5));   // next 256-row tile
                    gld = *reinterpret_cast<const float2*>(po_b + (size_t)(tb + 1) * 2048 + 2 * tid);
                }
            }
            if (ti == 6 && tb < NTB - 1) {
                const int s0 = (tb & 1) ? 0 : 8;   // opposite ring half
                *reinterpret_cast<float2*>(pring + s0 * 256 + 2 * tid) = gld;
            }

            // proj for this h (broadcast per quad; consumed after barrier A)
            const float pld = pring[((t & 15) << 8) + myh];

            // ---- phase 1: partial dots, coefficients from spike bytes.
            // j-ascending fma chains verbatim R6 (coefficients exactly 0/1).
            const uint4 cw = *reinterpret_cast<const uint4*>(
                sbyte + ((t & 1) << 8) + (w << 4));
            const uint32_t cws[4] = {cw.x, cw.y, cw.z, cw.w};
            float a0 = 0.f, a1 = 0.f, a2 = 0.f, a3 = 0.f;
#pragma unroll
            for (int j = 0; j < 16; ++j) {
                const float bf = (float)((cws[j >> 2] >> ((j & 3) * 8)) & 0xFFu);
                a0 = fmaf(bf, Vr[0][j], a0);
                a1 = fmaf(bf, Vr[1][j], a1);
                a2 = fmaf(bf, Vr[2][j], a2);
                a3 = fmaf(bf, Vr[3][j], a3);
            }
            float4 part; part.x = a0; part.y = a1; part.z = a2; part.w = a3;
            *reinterpret_cast<float4*>(pbuf + w * SSTRIDE + h0) = part;

            scan_bar();   // barrier A: partials visible

            // ---- phase 2 (ALL waves): quad-reduce for myh
            const float pp0 = pbuf[(4 * sub + 0) * SSTRIDE + myh];
            const float pp1 = pbuf[(4 * sub + 1) * SSTRIDE + myh];
            const float pp2 = pbuf[(4 * sub + 2) * SSTRIDE + myh];
            const float pp3 = pbuf[(4 * sub + 3) * SSTRIDE + myh];
            const float rsub = (pp0 + pp1) + (pp2 + pp3);     // r_sub of the tree
            const float u    = rsub + swz_xor1(rsub);         // r0+r1 / r2+r3
            const float rec0 = u + swz_xor2(u);               // (r0+r1)+(r2+r3)
            const float rec  = rec0 + br;

            const float p = pld;
            float m2;
            {
#pragma clang fp contract(off)
                const float input_ = p + spk;   // combined = proj + spk
                m2 = kBeta * mem;               // reference op order
                m2 = m2 + input_;
                m2 = m2 + rec;
                m2 = m2 - spk * kThr;           // reset == spk_prev exactly
            }
            const bool fire = (m2 > kThr);
            const float ns = fire ? 1.0f : 0.0f;
            if (sub == 0) {
                obuf[(ti << 8) + myh] = ns;                       // outbox
                sbyte[(((t & 1) ^ 1) << 8) + myh] = fire ? 1 : 0; // next coef
            }
            mem = m2;
            spk = ns;

            scan_bar();   // barrier B: new spike bytes + outbox slot visible
        }
    }

    // final burst: rows 2040..2047 from the outbox
    {
        const float2 d = *reinterpret_cast<const float2*>(obuf + 2 * tid);
        *reinterpret_cast<float2*>(po_b + (size_t)(NTB - 1) * 2048 + 2 * tid) = d;
    }
}

// ---------------------------------------------------------------------------
__global__ void __launch_bounds__(1024, 4)
fused(const float* __restrict__ x, const float* __restrict__ W,
      const float* __restrict__ b_in, const float* __restrict__ V,
      const float* __restrict__ b_rec, float* __restrict__ PO,
      int* flags, int n_scan)
{
    __shared__ __align__(16) float smem[SMEM_FLOATS];
    if ((int)blockIdx.x < n_scan) {
        scan_body(PO, V, b_rec, flags, smem);
    } else {
        gemm_body(x, W, b_in, PO, flags, (int)blockIdx.x - n_scan, smem);
    }
}

// ---------------------------------------------------------------------------
extern "C" void kernel_launch(void* const* d_in, const int* in_sizes, int n_in,
                              void* d_out, int out_size, void* d_ws, size_t ws_size,
                              hipStream_t stream) {
    const float* x     = (const float*)d_in[0];
    const float* W_in  = (const float*)d_in[1];
    const float* b_in  = (const float*)d_in[2];
    const float* V     = (const float*)d_in[3];
    const float* b_rec = (const float*)d_in[4];
    float* out = (float*)d_out;

    const size_t flag_bytes = (size_t)N_SCAN * FLAGS_PER_B * sizeof(int);
    if (ws_size >= flag_bytes) {
        int* flags = (int*)d_ws;
        hipMemsetAsync(flags, 0, flag_bytes, stream);   // ws is poisoned 0xAA
        fused<<<N_SCAN + N_GEMM, 1024, 0, stream>>>(x, W_in, b_in, V, b_rec,
                                                    out, flags, N_SCAN);
    } else {
        // fallback: sequential (no flags) — GEMM pass, then scan pass
        fused<<<N_GEMM, 1024, 0, stream>>>(x, W_in, b_in, V, b_rec, out, nullptr, 0);
        fused<<<N_SCAN, 1024, 0, stream>>>(x, W_in, b_in, V, b_rec, out, nullptr, N_SCAN);
    }
}

// Round 7
// 1555.316 us; speedup vs baseline: 1.2605x; 1.2605x over previous
//
#include <hip/hip_runtime.h>
#include <cstddef>
#include <cstdint>

// Problem constants
#define kB 32
#define kT 2048
#define kIn 512
#define kH 256
#define kBeta 0.85f
#define kThr 1.0f

// Fused-kernel layout: blocks [0, N_SCAN) = scan (one per batch),
// blocks [N_SCAN, N_SCAN+N_GEMM) = GEMM tiles (256x256, t-major order).
#define N_SCAN kB
#define N_GEMM (kB * 8)        // 32 b x 8 t_tiles (256 rows each)
#define FLAGS_PER_B 8
#define NTB (kT / 8)           // 256 bursts of 8 steps

// GEMM tile config: 256x256 tile, BK=16, 1024 threads, 8x8 micro-tile.
#define GBM 256
#define GBK 16
#define GLDA 260               // +4 pad: conflict-free transposed staging

// scan smem map (float offsets)
#define SSTRIDE 260            // pbuf row stride (2-way-free phase-2 reads)
#define PBUF_HALF (16 * SSTRIDE)        // 4160 floats per buffer
#define SM_PRING (2 * PBUF_HALF)        // 8320: proj ring, 16 slots x 256
#define SMEM_SCAN (SM_PRING + 16 * 256) // 12416 floats = 49.7 KB
#define SMEM_GEMM (2 * GBK * GLDA)      // 8320 floats
#define SMEM_FLOATS (SMEM_SCAN > SMEM_GEMM ? SMEM_SCAN : SMEM_GEMM)

__device__ __forceinline__ void wait_flag(int* f) {
    // acquire/agent: later proj loads must see the producer XCD's stores
    while (__hip_atomic_load(f, __ATOMIC_ACQUIRE, __HIP_MEMORY_SCOPE_AGENT) == 0) {
        __builtin_amdgcn_s_sleep(2);
    }
}

// Scan barrier: LDS-fence only (lgkmcnt(0) + raw s_barrier), proven in R11.
// Does NOT drain vmcnt, so proj prefetch loads / spike stores stay in
// flight across barriers. All cross-wave scan traffic is LDS.
__device__ __forceinline__ void scan_bar() {
    asm volatile("s_waitcnt lgkmcnt(0)" ::: "memory");
    __builtin_amdgcn_s_barrier();
}

// Quad butterfly via DPP quad_perm (VALU latency, no LDS pipe, no bank
// traffic). Pure lane routing -- numerics identical to R12's verified
// ds_swizzle path.
__device__ __forceinline__ float dpp_xor1(float x) {   // lanes 0123 -> 1032
    return __int_as_float(__builtin_amdgcn_update_dpp(
        0, __float_as_int(x), 0xB1, 0xF, 0xF, true));
}
__device__ __forceinline__ float dpp_xor2(float x) {   // lanes 0123 -> 2301
    return __int_as_float(__builtin_amdgcn_update_dpp(
        0, __float_as_int(x), 0x4E, 0xF, 0xF, true));
}

// ---------------------------------------------------------------------------
// GEMM body: proj tile = x(256xK) @ W_in^T(Kx256) + b_in, then publish flag.
// Verbatim from the verified round-6 kernel (bit-identical proj).
// ---------------------------------------------------------------------------
__device__ void gemm_body(const float* __restrict__ A,
                          const float* __restrict__ W,
                          const float* __restrict__ bias,
                          float* __restrict__ P,
                          int* flags, int gid, float* smem)
{
    float* As = smem;
    float* Bs = smem + GBK * GLDA;
    const int tid = threadIdx.x;
    const int b  = gid & 31;          // t-major tile order: all b at t_tile 0 first
    const int tt = gid >> 5;          // 0..7
    const int bm = b * kT + tt * GBM; // row offset in flattened (B*T)
    const int tx = tid & 31;
    const int ty = tid >> 5;          // 0..31

    float acc[8][8];
#pragma unroll
    for (int i = 0; i < 8; ++i)
#pragma unroll
        for (int j = 0; j < 8; ++j) acc[i][j] = 0.f;

    const int r = tid >> 2, kc = (tid & 3) << 2;

    for (int kb = 0; kb < kIn; kb += GBK) {
        const float4 av = *reinterpret_cast<const float4*>(A + (size_t)(bm + r) * kIn + kb + kc);
        const float4 bv = *reinterpret_cast<const float4*>(W + (size_t)r * kIn + kb + kc);
        __syncthreads();   // previous iteration's LDS reads done
        As[(kc + 0) * GLDA + r] = av.x;
        As[(kc + 1) * GLDA + r] = av.y;
        As[(kc + 2) * GLDA + r] = av.z;
        As[(kc + 3) * GLDA + r] = av.w;
        Bs[(kc + 0) * GLDA + r] = bv.x;
        Bs[(kc + 1) * GLDA + r] = bv.y;
        Bs[(kc + 2) * GLDA + r] = bv.z;
        Bs[(kc + 3) * GLDA + r] = bv.w;
        __syncthreads();

#pragma unroll
        for (int k = 0; k < GBK; ++k) {
            const float4 aa0 = *reinterpret_cast<const float4*>(&As[k * GLDA + ty * 4]);
            const float4 aa1 = *reinterpret_cast<const float4*>(&As[k * GLDA + ty * 4 + 128]);
            const float4 bb0 = *reinterpret_cast<const float4*>(&Bs[k * GLDA + tx * 4]);
            const float4 bb1 = *reinterpret_cast<const float4*>(&Bs[k * GLDA + tx * 4 + 128]);
            const float av8[8] = {aa0.x, aa0.y, aa0.z, aa0.w, aa1.x, aa1.y, aa1.z, aa1.w};
            const float bv8[8] = {bb0.x, bb0.y, bb0.z, bb0.w, bb1.x, bb1.y, bb1.z, bb1.w};
#pragma unroll
            for (int i = 0; i < 8; ++i)
#pragma unroll
                for (int j = 0; j < 8; ++j)
                    acc[i][j] = fmaf(av8[i], bv8[j], acc[i][j]);
        }
    }

    const float4 bl = *reinterpret_cast<const float4*>(bias + tx * 4);
    const float4 bh = *reinterpret_cast<const float4*>(bias + tx * 4 + 128);
#pragma unroll
    for (int i = 0; i < 8; ++i) {
        const int m = bm + ty * 4 + (i & 3) + ((i >> 2) << 7);
        float4 o0, o1;
        o0.x = acc[i][0] + bl.x; o0.y = acc[i][1] + bl.y;
        o0.z = acc[i][2] + bl.z; o0.w = acc[i][3] + bl.w;
        o1.x = acc[i][4] + bh.x; o1.y = acc[i][5] + bh.y;
        o1.z = acc[i][6] + bh.z; o1.w = acc[i][7] + bh.w;
        *reinterpret_cast<float4*>(P + (size_t)m * kH + tx * 4) = o0;
        *reinterpret_cast<float4*>(P + (size_t)m * kH + tx * 4 + 128) = o1;
    }

    __syncthreads();   // all stores executed block-wide
    if (flags && tid == 0) {
        __threadfence();                                  // device-scope release
        atomicAdd(flags + b * FLAGS_PER_B + tt, 1);       // publish (b, tt) ready
    }
}

// ---------------------------------------------------------------------------
// Scan, round 13: single-barrier step.
// Key alignment: wave w's phase-1 k-chunk [16w,16w+16) == the neurons wave
// w's distributed phase-2 owns, so the next-step spike mask comes straight
// from this wave's __ballot (SGPR) -- no LDS mask exchange, no readfirstlane,
// no second barrier. pbuf is DOUBLE-BUFFERED: phase-1(t) writes buf[t&1],
// one barrier, phase-2(t) reads buf[t&1]; phase-1(t+1) writes the other
// buffer, and barrier(t+1) orders the t+2 overwrite after all t reads.
// Phase-1 keeps R6's verified sparse nibble-skip expansion (ballot bit 4j =
// spike of neuron 16w+j; j-ascending fma chains; skipped terms have bf==0,
// fmaf(0,V,a)==a -> bit-identical). Phase-2 is R12's verified quad scheme
// (4 lanes/neuron; rsub=(s0+s1)+(s2+s3); quad halves summed commutatively
// into ((r0+r1)+(r2+r3))+br) with DPP quad_perm instead of ds_swizzle
// (pure lane routing, same bits, no LDS-pipe traffic). Update replicated
// per quad (verified); quad-leader stores the spike directly to global
// (64 B/wave coalesced, fire-and-forget -- no outbox, no drain).
// vmem: proj prefetch distributed over all 1024 threads (float2 per burst),
// issued at ti==0, LDS-written at ti==6, in flight across lgkm-only
// barriers (verified R12 discipline).
// ---------------------------------------------------------------------------
__device__ void scan_body(float* __restrict__ PO,
                          const float* __restrict__ V,
                          const float* __restrict__ brec,
                          int* flags, float* smem)
{
    float* pbuf  = smem;               // 2 x [16][SSTRIDE]
    float* pring = smem + SM_PRING;    // 16 slots x 256

    const int b = blockIdx.x;
    const int tid = threadIdx.x;
    const int w = tid >> 6;            // wave 0..15 = k-chunk / neuron group
    const int l = tid & 63;
    const int h0 = l << 2;             // phase-1: this thread's 4 h-rows
    const int kc = w << 4;             // phase-1: k base
    const int sub = l & 3;             // phase-2: quarter index
    const int myh = (w << 4) + (l >> 2);   // phase-2: owned neuron

    // V regs: Vr[i][c] = V[h0+i][kc+c]   (64 VGPRs; verbatim R6)
    float Vr[4][16];
#pragma unroll
    for (int i = 0; i < 4; ++i) {
        const float4* vp = reinterpret_cast<const float4*>(V + (size_t)(h0 + i) * kH + kc);
#pragma unroll
        for (int c4 = 0; c4 < 4; ++c4) {
            const float4 v = vp[c4];
            Vr[i][c4 * 4 + 0] = v.x; Vr[i][c4 * 4 + 1] = v.y;
            Vr[i][c4 * 4 + 2] = v.z; Vr[i][c4 * 4 + 3] = v.w;
        }
    }

    const float br = brec[myh];
    float mem = 0.f, spk = 0.f;
    unsigned long long bm = 0ull;      // this wave's spike chunk (bit 4j = spk[16w+j])
    float* po_b = PO + (size_t)b * (size_t)kT * kH;

    int* bflags = flags ? (flags + b * FLAGS_PER_B) : nullptr;

    // init: all threads stage proj rows 0..7 into ring slots 0..7
    if (bflags) wait_flag(bflags + 0);         // proj tile (b, t<256) ready
    {
        const float2 iv = *reinterpret_cast<const float2*>(po_b + 2 * tid);
        *reinterpret_cast<float2*>(pring + 2 * tid) = iv;
    }
    scan_bar();

    for (int tb = 0; tb < NTB; ++tb) {
        float2 gld;
#pragma unroll
        for (int ti = 0; ti < 8; ++ti) {
            const int t = tb * 8 + ti;

            // distributed proj prefetch: issue at ti==0, LDS-write at ti==6
            if (ti == 0 && tb < NTB - 1) {
                if (bflags && ((tb + 1) & 31) == 0)
                    wait_flag(bflags + ((tb + 1) >> 5));   // next 256-row tile
                gld = *reinterpret_cast<const float2*>(
                    po_b + (size_t)(tb + 1) * 2048 + 2 * tid);
            }
            if (ti == 6 && tb < NTB - 1) {
                const int s0 = (tb & 1) ? 0 : 8;   // opposite ring half
                *reinterpret_cast<float2*>(pring + s0 * 256 + 2 * tid) = gld;
            }

            // proj for this neuron (quad-broadcast; consumed after barrier)
            const float pld = pring[((t & 15) << 8) + myh];

            // ---- phase 1: sparse partial dots from this wave's own mask
            // (verbatim R6 nibble-skip; bm bit 4j = spk of neuron 16w+j)
            float a0 = 0.f, a1 = 0.f, a2 = 0.f, a3 = 0.f;
#pragma unroll
            for (int n = 0; n < 4; ++n) {
                const uint32_t nib = (uint32_t)(bm >> (16 * n)) & 0x1111u;
                if (nib) {                       // wave-uniform skip
#pragma unroll
                    for (int bit = 0; bit < 4; ++bit) {
                        const int j = 4 * n + bit;
                        const float bf = (float)((nib >> (4 * bit)) & 1u);
                        a0 = fmaf(bf, Vr[0][j], a0);
                        a1 = fmaf(bf, Vr[1][j], a1);
                        a2 = fmaf(bf, Vr[2][j], a2);
                        a3 = fmaf(bf, Vr[3][j], a3);
                    }
                }
            }
            float* pb = pbuf + (t & 1) * PBUF_HALF;
            float4 part; part.x = a0; part.y = a1; part.z = a2; part.w = a3;
            *reinterpret_cast<float4*>(pb + w * SSTRIDE + h0) = part;

            scan_bar();   // the ONE barrier: partials of buf[t&1] visible

            // ---- phase 2 (ALL waves): quad-reduce for myh
            const float pp0 = pb[(4 * sub + 0) * SSTRIDE + myh];
            const float pp1 = pb[(4 * sub + 1) * SSTRIDE + myh];
            const float pp2 = pb[(4 * sub + 2) * SSTRIDE + myh];
            const float pp3 = pb[(4 * sub + 3) * SSTRIDE + myh];
            const float rsub = (pp0 + pp1) + (pp2 + pp3);     // r_sub of the tree
            const float u1   = rsub + dpp_xor1(rsub);         // r0+r1 / r2+r3
            const float rec0 = u1 + dpp_xor2(u1);             // (r0+r1)+(r2+r3)
            const float rec  = rec0 + br;

            const float p = pld;
            float m2;
            {
#pragma clang fp contract(off)
                const float input_ = p + spk;   // combined = proj + spk
                m2 = kBeta * mem;               // reference op order
                m2 = m2 + input_;
                m2 = m2 + rec;
                m2 = m2 - spk * kThr;           // reset == spk_prev exactly
            }
            const bool fire = (m2 > kThr);
            const float ns = fire ? 1.0f : 0.0f;
            bm = __ballot(fire);               // next step's chunk, in SGPR
            if (sub == 0)
                po_b[(size_t)t * kH + myh] = ns;   // coalesced 64B/wave store
            mem = m2;
            spk = ns;
        }
    }
}

// ---------------------------------------------------------------------------
__global__ void __launch_bounds__(1024, 4)
fused(const float* __restrict__ x, const float* __restrict__ W,
      const float* __restrict__ b_in, const float* __restrict__ V,
      const float* __restrict__ b_rec, float* __restrict__ PO,
      int* flags, int n_scan)
{
    __shared__ __align__(16) float smem[SMEM_FLOATS];
    if ((int)blockIdx.x < n_scan) {
        scan_body(PO, V, b_rec, flags, smem);
    } else {
        gemm_body(x, W, b_in, PO, flags, (int)blockIdx.x - n_scan, smem);
    }
}

// ---------------------------------------------------------------------------
extern "C" void kernel_launch(void* const* d_in, const int* in_sizes, int n_in,
                              void* d_out, int out_size, void* d_ws, size_t ws_size,
                              hipStream_t stream) {
    const float* x     = (const float*)d_in[0];
    const float* W_in  = (const float*)d_in[1];
    const float* b_in  = (const float*)d_in[2];
    const float* V     = (const float*)d_in[3];
    const float* b_rec = (const float*)d_in[4];
    float* out = (float*)d_out;

    const size_t flag_bytes = (size_t)N_SCAN * FLAGS_PER_B * sizeof(int);
    if (ws_size >= flag_bytes) {
        int* flags = (int*)d_ws;
        hipMemsetAsync(flags, 0, flag_bytes, stream);   // ws is poisoned 0xAA
        fused<<<N_SCAN + N_GEMM, 1024, 0, stream>>>(x, W_in, b_in, V, b_rec,
                                                    out, flags, N_SCAN);
    } else {
        // fallback: sequential (no flags) — GEMM pass, then scan pass
        fused<<<N_GEMM, 1024, 0, stream>>>(x, W_in, b_in, V, b_rec, out, nullptr, 0);
        fused<<<N_SCAN, 1024, 0, stream>>>(x, W_in, b_in, V, b_rec, out, nullptr, N_SCAN);
    }
}